// Round 1
// 1801.059 us; speedup vs baseline: 1.1515x; 1.1515x over previous
//
#include <hip/hip_runtime.h>

#define NB 64
#define NW 32
#define NT 4096
#define ND 128

#define GI_STRIDE 388   // 384 + 4 pad (dwords): window stores land 2-way max
#define HR_STRIDE 144   // h-ring row stride in shorts (288 B, 16B-aligned)

typedef __attribute__((ext_vector_type(8))) short short8;
typedef __attribute__((ext_vector_type(4))) float f32x4;

// workgroup barrier that drains LDS ops only (no vmcnt(0) drain):
// in-flight global prefetch loads stay outstanding across steps.
#define BAR_LGKM() asm volatile("s_waitcnt lgkmcnt(0)\n\ts_barrier" ::: "memory")

static __device__ __forceinline__ float sigm_f(float v) {
    float e = __builtin_amdgcn_exp2f(v * -1.4426950408889634f);
    return __builtin_amdgcn_rcpf(1.0f + e);
}
static __device__ __forceinline__ float tanh_f(float v) {
    float e = __builtin_amdgcn_exp2f(v * 2.8853900817779268f);
    return 1.0f - 2.0f * __builtin_amdgcn_rcpf(1.0f + e);
}
static __device__ __forceinline__ unsigned short f2bf(float f) {
    unsigned u = __float_as_uint(f);
    u += 0x7FFFu + ((u >> 16) & 1u);
    return (unsigned short)(u >> 16);
}

// Kernel 1: d_out[b*T+t] = c2 + scale*noise[b,t] + sum_w x[b,w,t]*v[w]
__global__ __launch_bounds__(256) void k_xv(
    const float* __restrict__ x, const float* __restrict__ enc_w,
    const float* __restrict__ enc_b, const float* __restrict__ dec_w,
    const float* __restrict__ dec_b, const float* __restrict__ scale,
    const float* __restrict__ noise, float* __restrict__ out)
{
    __shared__ float v_s[NW];
    __shared__ float c2_s;
    const int tid = threadIdx.x;
    if (tid < NW) {
        float s = 0.0f;
        for (int d = 0; d < ND; ++d) s = fmaf(enc_w[d * NW + tid], dec_w[d], s);
        v_s[tid] = s;
    } else if (tid == 64) {
        float s = 0.0f;
        for (int d = 0; d < ND; ++d) s = fmaf(enc_b[d], dec_w[d], s);
        c2_s = s + dec_b[0];
    }
    __syncthreads();
    const int flat = blockIdx.x * 256 + tid;   // flat = b*NT + t
    const int b = flat >> 12;
    const int t = flat & (NT - 1);
    float acc = c2_s + scale[0] * noise[flat];
    const float* xr = x + (size_t)b * NW * NT + t;
    #pragma unroll
    for (int w = 0; w < NW; ++w) acc = fmaf(xr[(size_t)w * NT], v_s[w], acc);
    out[flat] = acc;
}

// Kernel 2: one block per batch element, 512 threads = 8 waves.
// Per step: 12 h-MFMAs per wave only. The x-side gi (rows-as-timesteps GEMM,
// 6 MFMAs/wave per 32 steps) is precomputed into a 64-row LDS double window
// at t%32==8; per-step gates read 3 broadcast f32 scalars. Decode is windowed:
// a 32-slot bf16 h-ring is decoded 16 timesteps at a time (4 MFMAs on a
// rotating duty wave at t%16==0) instead of 4 MFMAs every step.
__global__ __launch_bounds__(512, 2) void k_gru(
    const float* __restrict__ x, const float* __restrict__ enc_w,
    const float* __restrict__ enc_b, const float* __restrict__ w_ih,
    const float* __restrict__ w_hh, const float* __restrict__ b_ih,
    const float* __restrict__ b_hh, const float* __restrict__ dec_w,
    float* out)
{
    __shared__ alignas(16) float gi_lds[64 * GI_STRIDE];           // 99328 B (aliases enc_w staging)
    __shared__ float encb_s[ND];
    __shared__ alignas(16) unsigned short h_ring[32 * HR_STRIDE];  // bf16, 32-slot ring, padded rows
    __shared__ alignas(16) float xv_lds[NT];                       // non-recurrent part
    __shared__ alignas(16) float out_lds[NT];                      // raw decode dots

    const int tid  = threadIdx.x;
    const int b    = blockIdx.x;
    const int wv   = tid >> 6;
    const int lane = tid & 63;
    const int g    = lane >> 4;      // k-group 0..3
    const int c    = lane & 15;      // column in 16-wide tile
    const int d    = wv * 16 + c;    // owned hidden index

    const size_t xbase = (size_t)b * NW * NT;
    float* outb = out + (size_t)b * NT;
    float* encw_s = gi_lds;          // alias: init phase only

    // ---- init staging ----
    for (int i = tid; i < ND * NW; i += 512) encw_s[i] = enc_w[i];
    if (tid < ND) encb_s[tid] = enc_b[tid];
    for (int i = tid; i < 32 * HR_STRIDE; i += 512) h_ring[i] = 0;
    for (int i = tid; i < NT / 4; i += 512)
        ((float4*)xv_lds)[i] = ((const float4*)outb)[i];
    __syncthreads();

    // ---- B-frags from w_hh: B[k][j]; j = gatebase+d, k = kt*32+8g+i ----
    short8 BR[4], BZ[4], BN[4];
    #pragma unroll
    for (int kt = 0; kt < 4; ++kt) {
        const float* pr = w_hh + (size_t)(0*ND + d) * ND + kt*32 + g*8;
        const float* pz = w_hh + (size_t)(1*ND + d) * ND + kt*32 + g*8;
        const float* pn = w_hh + (size_t)(2*ND + d) * ND + kt*32 + g*8;
        #pragma unroll
        for (int i = 0; i < 8; ++i) {
            BR[kt][i] = (short)f2bf(pr[i]);
            BZ[kt][i] = (short)f2bf(pz[i]);
            BN[kt][i] = (short)f2bf(pn[i]);
        }
    }

    // ---- decode B-frags (replicated across cols): BD[kt][i] = dec_w[kt*32+8g+i] ----
    short8 BD[4];
    #pragma unroll
    for (int kt = 0; kt < 4; ++kt)
        #pragma unroll
        for (int i = 0; i < 8; ++i)
            BD[kt][i] = (short)f2bf(dec_w[kt*32 + g*8 + i]);

    // ---- fused input B-frags: M[w][j] = sum_dp enc_w[dp][w]*w_ih[j][dp] ----
    short8 XR, XZ, XN;
    {
        const float* rr = w_ih + (size_t)(0*ND + d) * ND;
        const float* rz = w_ih + (size_t)(1*ND + d) * ND;
        const float* rn = w_ih + (size_t)(2*ND + d) * ND;
        #pragma unroll
        for (int i = 0; i < 8; ++i) {
            int w = g*8 + i;
            float ar = 0.0f, az = 0.0f, an = 0.0f;
            for (int dp = 0; dp < ND; ++dp) {
                float ew = encw_s[dp*NW + w];
                ar = fmaf(ew, rr[dp], ar);
                az = fmaf(ew, rz[dp], az);
                an = fmaf(ew, rn[dp], an);
            }
            XR[i] = (short)f2bf(ar); XZ[i] = (short)f2bf(az); XN[i] = (short)f2bf(an);
        }
    }

    // ---- folded biases -> loop-invariant C vectors ----
    float cR, cZ, cGN, cIN;
    {
        const float* rr = w_ih + (size_t)(0*ND + d) * ND;
        const float* rz = w_ih + (size_t)(1*ND + d) * ND;
        const float* rn = w_ih + (size_t)(2*ND + d) * ND;
        float b0 = b_ih[d], b1 = b_ih[ND+d], b2 = b_ih[2*ND+d];
        for (int dp = 0; dp < ND; ++dp) {
            float eb = encb_s[dp];
            b0 = fmaf(eb, rr[dp], b0);
            b1 = fmaf(eb, rz[dp], b1);
            b2 = fmaf(eb, rn[dp], b2);
        }
        cR  = b0 + b_hh[d];
        cZ  = b1 + b_hh[ND+d];
        cGN = b_hh[2*ND+d];
        cIN = b2;
    }
    const f32x4 cRv  = {cR, cR, cR, cR};
    const f32x4 cZv  = {cZ, cZ, cZ, cZ};
    const f32x4 cGNv = {cGN, cGN, cGN, cGN};
    const f32x4 cINv = {cIN, cIN, cIN, cIN};
    const f32x4 zv   = {0.f, 0.f, 0.f, 0.f};

    __syncthreads();   // all waves done reading encw_s before gi_lds overwrite

    // ---- prologue: window 0 gi GEMM (rows = timesteps), then prefetch window 1 ----
    float xf[16];      // A-frag floats for the NEXT window, in flight
    #pragma unroll
    for (int q = 0; q < 16; ++q)
        xf[q] = x[xbase + (size_t)(g*8 + (q & 7)) * NT + ((q >> 3) * 16 + c)];
    {
        short8 xA0, xA1;
        #pragma unroll
        for (int i = 0; i < 8; ++i) { xA0[i] = (short)f2bf(xf[i]); xA1[i] = (short)f2bf(xf[8+i]); }
        f32x4 gR0 = __builtin_amdgcn_mfma_f32_16x16x32_bf16(xA0, XR, cRv, 0, 0, 0);
        f32x4 gR1 = __builtin_amdgcn_mfma_f32_16x16x32_bf16(xA1, XR, cRv, 0, 0, 0);
        f32x4 gZ0 = __builtin_amdgcn_mfma_f32_16x16x32_bf16(xA0, XZ, cZv, 0, 0, 0);
        f32x4 gZ1 = __builtin_amdgcn_mfma_f32_16x16x32_bf16(xA1, XZ, cZv, 0, 0, 0);
        f32x4 gN0 = __builtin_amdgcn_mfma_f32_16x16x32_bf16(xA0, XN, cINv, 0, 0, 0);
        f32x4 gN1 = __builtin_amdgcn_mfma_f32_16x16x32_bf16(xA1, XN, cINv, 0, 0, 0);
        #pragma unroll
        for (int r = 0; r < 4; ++r) {
            int ti = 4*g + r;
            gi_lds[(ti     )*GI_STRIDE +       d] = gR0[r];
            gi_lds[(ti     )*GI_STRIDE + 128 + d] = gZ0[r];
            gi_lds[(ti     )*GI_STRIDE + 256 + d] = gN0[r];
            gi_lds[(ti + 16)*GI_STRIDE +       d] = gR1[r];
            gi_lds[(ti + 16)*GI_STRIDE + 128 + d] = gZ1[r];
            gi_lds[(ti + 16)*GI_STRIDE + 256 + d] = gN1[r];
        }
    }
    #pragma unroll
    for (int q = 0; q < 16; ++q)
        xf[q] = x[xbase + (size_t)(g*8 + (q & 7)) * NT + (32 + (q >> 3) * 16 + c)];

    __syncthreads();

    float h = 0.0f;

    #pragma unroll 1
    for (int t = 0; t < NT; ++t) {
        // ---- h A-frags (broadcast b128 reads from ring slot (t-1)&31) ----
        const short8* hp = (const short8*)(h_ring + (size_t)((t + 31) & 31) * HR_STRIDE);
        const short8 HA0 = hp[0*4 + g];
        const short8 HA1 = hp[1*4 + g];
        const short8 HA2 = hp[2*4 + g];
        const short8 HA3 = hp[3*4 + g];

        // ---- gi scalars for this step (broadcast reads, hidden under MFMA issue) ----
        const float* gp = gi_lds + (size_t)(t & 63) * GI_STRIDE + d;
        const float giR = gp[0];
        const float giZ = gp[128];
        const float giN = gp[256];

        // ---- 12 h-MFMAs: R chains first, then Z, then N (early-R for sigm) ----
        f32x4 aR1 = __builtin_amdgcn_mfma_f32_16x16x32_bf16(HA0, BR[0], zv,  0, 0, 0);
        f32x4 aR2 = __builtin_amdgcn_mfma_f32_16x16x32_bf16(HA2, BR[2], zv,  0, 0, 0);
        aR1 = __builtin_amdgcn_mfma_f32_16x16x32_bf16(HA1, BR[1], aR1, 0, 0, 0);
        aR2 = __builtin_amdgcn_mfma_f32_16x16x32_bf16(HA3, BR[3], aR2, 0, 0, 0);
        f32x4 aZ1 = __builtin_amdgcn_mfma_f32_16x16x32_bf16(HA0, BZ[0], zv,  0, 0, 0);
        f32x4 aZ2 = __builtin_amdgcn_mfma_f32_16x16x32_bf16(HA2, BZ[2], zv,  0, 0, 0);
        aZ1 = __builtin_amdgcn_mfma_f32_16x16x32_bf16(HA1, BZ[1], aZ1, 0, 0, 0);
        aZ2 = __builtin_amdgcn_mfma_f32_16x16x32_bf16(HA3, BZ[3], aZ2, 0, 0, 0);
        f32x4 aN1 = __builtin_amdgcn_mfma_f32_16x16x32_bf16(HA0, BN[0], cGNv, 0, 0, 0);
        f32x4 aN2 = __builtin_amdgcn_mfma_f32_16x16x32_bf16(HA2, BN[2], zv,  0, 0, 0);
        aN1 = __builtin_amdgcn_mfma_f32_16x16x32_bf16(HA1, BN[1], aN1, 0, 0, 0);
        aN2 = __builtin_amdgcn_mfma_f32_16x16x32_bf16(HA3, BN[3], aN2, 0, 0, 0);

        // ---- next-window gi GEMM at t%32==8 (off decode steps; stores have
        //      24 steps of slack -> no lgkm stall; loads 32 steps of slack) ----
        if ((t & 31) == 8) {
            const int t0n = (t & ~31) + 32;
            if (t0n < NT) {
                short8 xA0, xA1;
                #pragma unroll
                for (int i = 0; i < 8; ++i) { xA0[i] = (short)f2bf(xf[i]); xA1[i] = (short)f2bf(xf[8+i]); }
                f32x4 gR0 = __builtin_amdgcn_mfma_f32_16x16x32_bf16(xA0, XR, cRv, 0, 0, 0);
                f32x4 gR1 = __builtin_amdgcn_mfma_f32_16x16x32_bf16(xA1, XR, cRv, 0, 0, 0);
                f32x4 gZ0 = __builtin_amdgcn_mfma_f32_16x16x32_bf16(xA0, XZ, cZv, 0, 0, 0);
                f32x4 gZ1 = __builtin_amdgcn_mfma_f32_16x16x32_bf16(xA1, XZ, cZv, 0, 0, 0);
                f32x4 gN0 = __builtin_amdgcn_mfma_f32_16x16x32_bf16(xA0, XN, cINv, 0, 0, 0);
                f32x4 gN1 = __builtin_amdgcn_mfma_f32_16x16x32_bf16(xA1, XN, cINv, 0, 0, 0);
                const int rbw = t0n & 63;
                #pragma unroll
                for (int r = 0; r < 4; ++r) {
                    int ti = rbw + 4*g + r;
                    gi_lds[(ti     )*GI_STRIDE +       d] = gR0[r];
                    gi_lds[(ti     )*GI_STRIDE + 128 + d] = gZ0[r];
                    gi_lds[(ti     )*GI_STRIDE + 256 + d] = gN0[r];
                    gi_lds[(ti + 16)*GI_STRIDE +       d] = gR1[r];
                    gi_lds[(ti + 16)*GI_STRIDE + 128 + d] = gZ1[r];
                    gi_lds[(ti + 16)*GI_STRIDE + 256 + d] = gN1[r];
                }
                const int t0p = t0n + 32;
                if (t0p < NT) {
                    #pragma unroll
                    for (int q = 0; q < 16; ++q)
                        xf[q] = x[xbase + (size_t)(g*8 + (q & 7)) * NT + (t0p + (q >> 3) * 16 + c)];
                }
            }
        }

        // ---- windowed decode: 16 past h's, rotating duty wave, fills gate-wait ----
        if ((t & 15) == 0 && t >= 16 && wv == (((t >> 4) - 1) & 7)) {
            const short8* hq = (const short8*)(h_ring + (size_t)(((t - 16) & 31) + c) * HR_STRIDE);
            short8 AD0 = hq[0*4 + g];
            short8 AD1 = hq[1*4 + g];
            short8 AD2 = hq[2*4 + g];
            short8 AD3 = hq[3*4 + g];
            f32x4 aD1 = __builtin_amdgcn_mfma_f32_16x16x32_bf16(AD0, BD[0], zv, 0, 0, 0);
            f32x4 aD2 = __builtin_amdgcn_mfma_f32_16x16x32_bf16(AD2, BD[2], zv, 0, 0, 0);
            aD1 = __builtin_amdgcn_mfma_f32_16x16x32_bf16(AD1, BD[1], aD1, 0, 0, 0);
            aD2 = __builtin_amdgcn_mfma_f32_16x16x32_bf16(AD3, BD[3], aD2, 0, 0, 0);
            if (c == 0) {
                #pragma unroll
                for (int r = 0; r < 4; ++r)
                    out_lds[(t - 16) + 4*g + r] = aD1[r] + aD2[r];
            }
        }

        // ---- gates + h update (R available earliest) ----
        float R  = aR1[0] + aR2[0] + giR;
        float r_ = sigm_f(R);
        float Z  = aZ1[0] + aZ2[0] + giZ;
        float z_ = sigm_f(Z);
        float GN = aN1[0] + aN2[0];
        float n_ = tanh_f(fmaf(r_, GN, giN));
        h = fmaf(z_, h - n_, n_);            // (1-z)*n + z*h
        if (lane < 16) h_ring[(size_t)(t & 31) * HR_STRIDE + d] = f2bf(h);
        BAR_LGKM();
    }

    // ---- epilogue: decode h_{NT-16..NT-1} (ring slots 16..31) ----
    if (wv == 7) {
        const short8* hq = (const short8*)(h_ring + (size_t)(16 + c) * HR_STRIDE);
        short8 AD0 = hq[0*4 + g];
        short8 AD1 = hq[1*4 + g];
        short8 AD2 = hq[2*4 + g];
        short8 AD3 = hq[3*4 + g];
        f32x4 aD1 = __builtin_amdgcn_mfma_f32_16x16x32_bf16(AD0, BD[0], zv, 0, 0, 0);
        f32x4 aD2 = __builtin_amdgcn_mfma_f32_16x16x32_bf16(AD2, BD[2], zv, 0, 0, 0);
        aD1 = __builtin_amdgcn_mfma_f32_16x16x32_bf16(AD1, BD[1], aD1, 0, 0, 0);
        aD2 = __builtin_amdgcn_mfma_f32_16x16x32_bf16(AD3, BD[3], aD2, 0, 0, 0);
        if (c == 0) {
            #pragma unroll
            for (int r = 0; r < 4; ++r)
                out_lds[(NT - 16) + 4*g + r] = aD1[r] + aD2[r];
        }
    }
    __syncthreads();
    // ---- flush: fuse +xv and relu ----
    for (int i = tid; i < NT / 4; i += 512) {
        float4 o = ((const float4*)out_lds)[i];
        float4 v = ((const float4*)xv_lds)[i];
        float4 r;
        r.x = fmaxf(o.x + v.x, 0.0f);
        r.y = fmaxf(o.y + v.y, 0.0f);
        r.z = fmaxf(o.z + v.z, 0.0f);
        r.w = fmaxf(o.w + v.w, 0.0f);
        ((float4*)outb)[i] = r;
    }
}

extern "C" void kernel_launch(void* const* d_in, const int* in_sizes, int n_in,
                              void* d_out, int out_size, void* d_ws, size_t ws_size,
                              hipStream_t stream) {
    const float* x      = (const float*)d_in[0];
    const float* enc_w  = (const float*)d_in[1];
    const float* enc_b  = (const float*)d_in[2];
    const float* w_ih   = (const float*)d_in[3];
    const float* w_hh   = (const float*)d_in[4];
    const float* b_ih   = (const float*)d_in[5];
    const float* b_hh   = (const float*)d_in[6];
    const float* dec_w  = (const float*)d_in[7];
    const float* dec_b  = (const float*)d_in[8];
    const float* scale  = (const float*)d_in[9];
    const float* noise  = (const float*)d_in[10];
    float* out = (float*)d_out;

    k_xv<<<(NB * NT) / 256, 256, 0, stream>>>(x, enc_w, enc_b, dec_w, dec_b, scale, noise, out);
    k_gru<<<NB, 512, 0, stream>>>(x, enc_w, enc_b, w_ih, w_hh, b_ih, b_hh, dec_w, out);
}

// Round 2
// 1763.977 us; speedup vs baseline: 1.1757x; 1.0210x over previous
//
#include <hip/hip_runtime.h>

#define NB 64
#define NW 32
#define NT 4096
#define ND 128

#define GI_DW 516       // gi row stride in dwords: 128 dims * 4 (R,Z,N,pad) + 4 pad
#define HR_STRIDE 144   // h-ring row stride in shorts (288 B, 16B-aligned)

typedef __attribute__((ext_vector_type(8))) short short8;
typedef __attribute__((ext_vector_type(4))) float f32x4;

// workgroup barrier that drains LDS ops only (no vmcnt(0) drain):
// in-flight global prefetch loads stay outstanding across steps.
#define BAR_LGKM() asm volatile("s_waitcnt lgkmcnt(0)\n\ts_barrier" ::: "memory")

static __device__ __forceinline__ float sigm_f(float v) {
    float e = __builtin_amdgcn_exp2f(v * -1.4426950408889634f);
    return __builtin_amdgcn_rcpf(1.0f + e);
}
static __device__ __forceinline__ float tanh_f(float v) {
    float e = __builtin_amdgcn_exp2f(v * 2.8853900817779268f);
    return 1.0f - 2.0f * __builtin_amdgcn_rcpf(1.0f + e);
}
static __device__ __forceinline__ unsigned short f2bf(float f) {
    unsigned u = __float_as_uint(f);
    u += 0x7FFFu + ((u >> 16) & 1u);
    return (unsigned short)(u >> 16);
}

// Kernel 1: d_out[b*T+t] = c2 + scale*noise[b,t] + sum_w x[b,w,t]*v[w]
__global__ __launch_bounds__(256) void k_xv(
    const float* __restrict__ x, const float* __restrict__ enc_w,
    const float* __restrict__ enc_b, const float* __restrict__ dec_w,
    const float* __restrict__ dec_b, const float* __restrict__ scale,
    const float* __restrict__ noise, float* __restrict__ out)
{
    __shared__ float v_s[NW];
    __shared__ float c2_s;
    const int tid = threadIdx.x;
    if (tid < NW) {
        float s = 0.0f;
        for (int d = 0; d < ND; ++d) s = fmaf(enc_w[d * NW + tid], dec_w[d], s);
        v_s[tid] = s;
    } else if (tid == 64) {
        float s = 0.0f;
        for (int d = 0; d < ND; ++d) s = fmaf(enc_b[d], dec_w[d], s);
        c2_s = s + dec_b[0];
    }
    __syncthreads();
    const int flat = blockIdx.x * 256 + tid;   // flat = b*NT + t
    const int b = flat >> 12;
    const int t = flat & (NT - 1);
    float acc = c2_s + scale[0] * noise[flat];
    const float* xr = x + (size_t)b * NW * NT + t;
    #pragma unroll
    for (int w = 0; w < NW; ++w) acc = fmaf(xr[(size_t)w * NT], v_s[w], acc);
    out[flat] = acc;
}

// Kernel 2: one block per batch element, 256 threads = 4 waves.
// Each wave owns 32 hidden dims (two 16-col tiles sharing broadcast h A-frags).
// Per step per wave: 4 HA ds_read_b128 + 1 packed-gi ds_read_b128 + 24 MFMAs +
// one gate chain per lane (g-odd lanes take tile 1) + 1 h ds_write_b16.
// gi (x-side gates) precomputed 16 timesteps at a time (rows-as-timesteps GEMM,
// 6 MFMAs/wave per 16 steps) in the post-h-write shadow; decode likewise
// windowed (4 MFMAs per 16 steps on a rotating duty wave).
__global__ __launch_bounds__(256, 1) void k_gru(
    const float* __restrict__ x, const float* __restrict__ enc_w,
    const float* __restrict__ enc_b, const float* __restrict__ w_ih,
    const float* __restrict__ w_hh, const float* __restrict__ b_ih,
    const float* __restrict__ b_hh, const float* __restrict__ dec_w,
    float* out)
{
    __shared__ alignas(16) float gi_lds[32 * GI_DW];               // 66048 B (aliases enc_w staging)
    __shared__ float encb_s[ND];
    __shared__ alignas(16) unsigned short h_ring[32 * HR_STRIDE];  // bf16, 32-slot ring, padded rows
    __shared__ alignas(16) float xv_lds[NT];                       // non-recurrent part
    __shared__ alignas(16) float out_lds[NT];                      // raw decode dots

    const int tid  = threadIdx.x;
    const int b    = blockIdx.x;
    const int wv   = tid >> 6;       // 0..3
    const int lane = tid & 63;
    const int g    = lane >> 4;      // k-group 0..3
    const int c    = lane & 15;      // column in 16-wide tile
    const int hi   = g & 1;          // which tile this lane's gate chain handles
    const int d0   = wv * 32 + c;        // tile-0 owned hidden index
    const int d1   = d0 + 16;            // tile-1 owned hidden index
    const int dl   = wv * 32 + (lane & 31);  // this lane's gate dim

    const size_t xbase = (size_t)b * NW * NT;
    float* outb = out + (size_t)b * NT;
    float* encw_s = gi_lds;          // alias: init phase only

    // ---- init staging ----
    for (int i = tid; i < ND * NW; i += 256) encw_s[i] = enc_w[i];
    if (tid < ND) encb_s[tid] = enc_b[tid];
    for (int i = tid; i < 32 * HR_STRIDE; i += 256) h_ring[i] = 0;
    for (int i = tid; i < NT / 4; i += 256)
        ((float4*)xv_lds)[i] = ((const float4*)outb)[i];
    __syncthreads();

    // ---- B-frags from w_hh: B[k][j]; j = gatebase+d, k = kt*32+8g+i ----
    short8 BR0[4], BZ0[4], BN0[4], BR1[4], BZ1[4], BN1[4];
    #pragma unroll
    for (int kt = 0; kt < 4; ++kt) {
        const float* pr0 = w_hh + (size_t)(0*ND + d0) * ND + kt*32 + g*8;
        const float* pz0 = w_hh + (size_t)(1*ND + d0) * ND + kt*32 + g*8;
        const float* pn0 = w_hh + (size_t)(2*ND + d0) * ND + kt*32 + g*8;
        const float* pr1 = w_hh + (size_t)(0*ND + d1) * ND + kt*32 + g*8;
        const float* pz1 = w_hh + (size_t)(1*ND + d1) * ND + kt*32 + g*8;
        const float* pn1 = w_hh + (size_t)(2*ND + d1) * ND + kt*32 + g*8;
        #pragma unroll
        for (int i = 0; i < 8; ++i) {
            BR0[kt][i] = (short)f2bf(pr0[i]);
            BZ0[kt][i] = (short)f2bf(pz0[i]);
            BN0[kt][i] = (short)f2bf(pn0[i]);
            BR1[kt][i] = (short)f2bf(pr1[i]);
            BZ1[kt][i] = (short)f2bf(pz1[i]);
            BN1[kt][i] = (short)f2bf(pn1[i]);
        }
    }

    // ---- decode B-frags (replicated across cols): BD[kt][i] = dec_w[kt*32+8g+i] ----
    short8 BD[4];
    #pragma unroll
    for (int kt = 0; kt < 4; ++kt)
        #pragma unroll
        for (int i = 0; i < 8; ++i)
            BD[kt][i] = (short)f2bf(dec_w[kt*32 + g*8 + i]);

    // ---- fused input B-frags: M[w][j] = sum_dp enc_w[dp][w]*w_ih[j][dp] ----
    short8 XR0, XZ0, XN0, XR1, XZ1, XN1;
    {
        const float* rr0 = w_ih + (size_t)(0*ND + d0) * ND;
        const float* rz0 = w_ih + (size_t)(1*ND + d0) * ND;
        const float* rn0 = w_ih + (size_t)(2*ND + d0) * ND;
        const float* rr1 = w_ih + (size_t)(0*ND + d1) * ND;
        const float* rz1 = w_ih + (size_t)(1*ND + d1) * ND;
        const float* rn1 = w_ih + (size_t)(2*ND + d1) * ND;
        #pragma unroll
        for (int i = 0; i < 8; ++i) {
            int w = g*8 + i;
            float ar0 = 0.f, az0 = 0.f, an0 = 0.f, ar1 = 0.f, az1 = 0.f, an1 = 0.f;
            for (int dp = 0; dp < ND; ++dp) {
                float ew = encw_s[dp*NW + w];
                ar0 = fmaf(ew, rr0[dp], ar0);
                az0 = fmaf(ew, rz0[dp], az0);
                an0 = fmaf(ew, rn0[dp], an0);
                ar1 = fmaf(ew, rr1[dp], ar1);
                az1 = fmaf(ew, rz1[dp], az1);
                an1 = fmaf(ew, rn1[dp], an1);
            }
            XR0[i] = (short)f2bf(ar0); XZ0[i] = (short)f2bf(az0); XN0[i] = (short)f2bf(an0);
            XR1[i] = (short)f2bf(ar1); XZ1[i] = (short)f2bf(az1); XN1[i] = (short)f2bf(an1);
        }
    }

    // ---- folded biases (per tile) -> loop-invariant C vectors ----
    float cR0, cZ0, cGN0, cIN0, cR1, cZ1, cGN1, cIN1;
    {
        const float* rr0 = w_ih + (size_t)(0*ND + d0) * ND;
        const float* rz0 = w_ih + (size_t)(1*ND + d0) * ND;
        const float* rn0 = w_ih + (size_t)(2*ND + d0) * ND;
        const float* rr1 = w_ih + (size_t)(0*ND + d1) * ND;
        const float* rz1 = w_ih + (size_t)(1*ND + d1) * ND;
        const float* rn1 = w_ih + (size_t)(2*ND + d1) * ND;
        float a0 = b_ih[d0], a1 = b_ih[ND+d0], a2 = b_ih[2*ND+d0];
        float e0 = b_ih[d1], e1 = b_ih[ND+d1], e2 = b_ih[2*ND+d1];
        for (int dp = 0; dp < ND; ++dp) {
            float eb = encb_s[dp];
            a0 = fmaf(eb, rr0[dp], a0);
            a1 = fmaf(eb, rz0[dp], a1);
            a2 = fmaf(eb, rn0[dp], a2);
            e0 = fmaf(eb, rr1[dp], e0);
            e1 = fmaf(eb, rz1[dp], e1);
            e2 = fmaf(eb, rn1[dp], e2);
        }
        cR0  = a0 + b_hh[d0];
        cZ0  = a1 + b_hh[ND+d0];
        cGN0 = b_hh[2*ND+d0];
        cIN0 = a2;
        cR1  = e0 + b_hh[d1];
        cZ1  = e1 + b_hh[ND+d1];
        cGN1 = b_hh[2*ND+d1];
        cIN1 = e2;
    }
    const f32x4 cRv0  = {cR0, cR0, cR0, cR0};
    const f32x4 cZv0  = {cZ0, cZ0, cZ0, cZ0};
    const f32x4 cGNv0 = {cGN0, cGN0, cGN0, cGN0};
    const f32x4 cINv0 = {cIN0, cIN0, cIN0, cIN0};
    const f32x4 cRv1  = {cR1, cR1, cR1, cR1};
    const f32x4 cZv1  = {cZ1, cZ1, cZ1, cZ1};
    const f32x4 cGNv1 = {cGN1, cGN1, cGN1, cGN1};
    const f32x4 cINv1 = {cIN1, cIN1, cIN1, cIN1};
    const f32x4 zv    = {0.f, 0.f, 0.f, 0.f};

    __syncthreads();   // all waves done reading encw_s before gi_lds overwrite

    // ---- prologue: half-0 gi GEMM (rows = timesteps 0..15), preload half-1 ----
    float xf[8];       // A-frag floats for the NEXT half, in flight
    #pragma unroll
    for (int q = 0; q < 8; ++q)
        xf[q] = x[xbase + (size_t)(g*8 + q) * NT + c];
    {
        short8 xA;
        #pragma unroll
        for (int i = 0; i < 8; ++i) xA[i] = (short)f2bf(xf[i]);
        f32x4 gR0 = __builtin_amdgcn_mfma_f32_16x16x32_bf16(xA, XR0, cRv0, 0, 0, 0);
        f32x4 gZ0 = __builtin_amdgcn_mfma_f32_16x16x32_bf16(xA, XZ0, cZv0, 0, 0, 0);
        f32x4 gN0 = __builtin_amdgcn_mfma_f32_16x16x32_bf16(xA, XN0, cINv0, 0, 0, 0);
        f32x4 gR1 = __builtin_amdgcn_mfma_f32_16x16x32_bf16(xA, XR1, cRv1, 0, 0, 0);
        f32x4 gZ1 = __builtin_amdgcn_mfma_f32_16x16x32_bf16(xA, XZ1, cZv1, 0, 0, 0);
        f32x4 gN1 = __builtin_amdgcn_mfma_f32_16x16x32_bf16(xA, XN1, cINv1, 0, 0, 0);
        #pragma unroll
        for (int r = 0; r < 4; ++r) {
            int ti = 4*g + r;
            f32x4 p0 = {gR0[r], gZ0[r], gN0[r], 0.f};
            f32x4 p1 = {gR1[r], gZ1[r], gN1[r], 0.f};
            *(f32x4*)(gi_lds + (size_t)ti * GI_DW + d0 * 4) = p0;
            *(f32x4*)(gi_lds + (size_t)ti * GI_DW + d1 * 4) = p1;
        }
    }
    #pragma unroll
    for (int q = 0; q < 8; ++q)
        xf[q] = x[xbase + (size_t)(g*8 + q) * NT + 16 + c];

    __syncthreads();

    float h = 0.0f;

    #pragma unroll 1
    for (int t = 0; t < NT; ++t) {
        // ---- h A-frags (broadcast b128 reads from ring slot (t-1)&31) ----
        const short8* hp = (const short8*)(h_ring + (size_t)((t + 31) & 31) * HR_STRIDE);
        const short8 HA0 = hp[0*4 + g];
        const short8 HA1 = hp[1*4 + g];
        const short8 HA2 = hp[2*4 + g];
        const short8 HA3 = hp[3*4 + g];

        // ---- packed gi for this lane's dim (one b128: {R,Z,N,pad}) ----
        const f32x4 giv = *(const f32x4*)(gi_lds + (size_t)(t & 31) * GI_DW + dl * 4);

        // ---- 24 h-MFMAs: R tiles first (early sigm), then Z, then N ----
        f32x4 aR1_0 = __builtin_amdgcn_mfma_f32_16x16x32_bf16(HA0, BR0[0], zv, 0, 0, 0);
        f32x4 aR2_0 = __builtin_amdgcn_mfma_f32_16x16x32_bf16(HA2, BR0[2], zv, 0, 0, 0);
        f32x4 aR1_1 = __builtin_amdgcn_mfma_f32_16x16x32_bf16(HA0, BR1[0], zv, 0, 0, 0);
        f32x4 aR2_1 = __builtin_amdgcn_mfma_f32_16x16x32_bf16(HA2, BR1[2], zv, 0, 0, 0);
        aR1_0 = __builtin_amdgcn_mfma_f32_16x16x32_bf16(HA1, BR0[1], aR1_0, 0, 0, 0);
        aR2_0 = __builtin_amdgcn_mfma_f32_16x16x32_bf16(HA3, BR0[3], aR2_0, 0, 0, 0);
        aR1_1 = __builtin_amdgcn_mfma_f32_16x16x32_bf16(HA1, BR1[1], aR1_1, 0, 0, 0);
        aR2_1 = __builtin_amdgcn_mfma_f32_16x16x32_bf16(HA3, BR1[3], aR2_1, 0, 0, 0);
        f32x4 aZ1_0 = __builtin_amdgcn_mfma_f32_16x16x32_bf16(HA0, BZ0[0], zv, 0, 0, 0);
        f32x4 aZ2_0 = __builtin_amdgcn_mfma_f32_16x16x32_bf16(HA2, BZ0[2], zv, 0, 0, 0);
        f32x4 aZ1_1 = __builtin_amdgcn_mfma_f32_16x16x32_bf16(HA0, BZ1[0], zv, 0, 0, 0);
        f32x4 aZ2_1 = __builtin_amdgcn_mfma_f32_16x16x32_bf16(HA2, BZ1[2], zv, 0, 0, 0);
        aZ1_0 = __builtin_amdgcn_mfma_f32_16x16x32_bf16(HA1, BZ0[1], aZ1_0, 0, 0, 0);
        aZ2_0 = __builtin_amdgcn_mfma_f32_16x16x32_bf16(HA3, BZ0[3], aZ2_0, 0, 0, 0);
        aZ1_1 = __builtin_amdgcn_mfma_f32_16x16x32_bf16(HA1, BZ1[1], aZ1_1, 0, 0, 0);
        aZ2_1 = __builtin_amdgcn_mfma_f32_16x16x32_bf16(HA3, BZ1[3], aZ2_1, 0, 0, 0);
        f32x4 aN1_0 = __builtin_amdgcn_mfma_f32_16x16x32_bf16(HA0, BN0[0], cGNv0, 0, 0, 0);
        f32x4 aN2_0 = __builtin_amdgcn_mfma_f32_16x16x32_bf16(HA2, BN0[2], zv, 0, 0, 0);
        f32x4 aN1_1 = __builtin_amdgcn_mfma_f32_16x16x32_bf16(HA0, BN1[0], cGNv1, 0, 0, 0);
        f32x4 aN2_1 = __builtin_amdgcn_mfma_f32_16x16x32_bf16(HA2, BN1[2], zv, 0, 0, 0);
        aN1_0 = __builtin_amdgcn_mfma_f32_16x16x32_bf16(HA1, BN0[1], aN1_0, 0, 0, 0);
        aN2_0 = __builtin_amdgcn_mfma_f32_16x16x32_bf16(HA3, BN0[3], aN2_0, 0, 0, 0);
        aN1_1 = __builtin_amdgcn_mfma_f32_16x16x32_bf16(HA1, BN1[1], aN1_1, 0, 0, 0);
        aN2_1 = __builtin_amdgcn_mfma_f32_16x16x32_bf16(HA3, BN1[3], aN2_1, 0, 0, 0);

        // ---- one gate chain per lane (g-odd lanes take tile 1) ----
        float R  = hi ? (aR1_1[0] + aR2_1[0]) : (aR1_0[0] + aR2_0[0]);
        float Z  = hi ? (aZ1_1[0] + aZ2_1[0]) : (aZ1_0[0] + aZ2_0[0]);
        float GN = hi ? (aN1_1[0] + aN2_1[0]) : (aN1_0[0] + aN2_0[0]);
        float r_ = sigm_f(R + giv[0]);
        float z_ = sigm_f(Z + giv[1]);
        float n_ = tanh_f(fmaf(r_, GN, giv[2]));
        h = fmaf(z_, h - n_, n_);            // (1-z)*n + z*h
        if (lane < 32) h_ring[(size_t)(t & 31) * HR_STRIDE + dl] = f2bf(h);

        // ---- next-half gi GEMM at t%16==8 (post-write shadow; stores have
        //      8 steps of slack; xf loads 24 steps of slack, no vmcnt drain) ----
        if ((t & 15) == 8) {
            const int t0n = (t & ~15) + 16;
            if (t0n < NT) {
                short8 xA;
                #pragma unroll
                for (int i = 0; i < 8; ++i) xA[i] = (short)f2bf(xf[i]);
                f32x4 gR0 = __builtin_amdgcn_mfma_f32_16x16x32_bf16(xA, XR0, cRv0, 0, 0, 0);
                f32x4 gZ0 = __builtin_amdgcn_mfma_f32_16x16x32_bf16(xA, XZ0, cZv0, 0, 0, 0);
                f32x4 gN0 = __builtin_amdgcn_mfma_f32_16x16x32_bf16(xA, XN0, cINv0, 0, 0, 0);
                f32x4 gR1 = __builtin_amdgcn_mfma_f32_16x16x32_bf16(xA, XR1, cRv1, 0, 0, 0);
                f32x4 gZ1 = __builtin_amdgcn_mfma_f32_16x16x32_bf16(xA, XZ1, cZv1, 0, 0, 0);
                f32x4 gN1 = __builtin_amdgcn_mfma_f32_16x16x32_bf16(xA, XN1, cINv1, 0, 0, 0);
                const int rb = t0n & 31;
                #pragma unroll
                for (int r = 0; r < 4; ++r) {
                    int ti = rb + 4*g + r;
                    f32x4 p0 = {gR0[r], gZ0[r], gN0[r], 0.f};
                    f32x4 p1 = {gR1[r], gZ1[r], gN1[r], 0.f};
                    *(f32x4*)(gi_lds + (size_t)ti * GI_DW + d0 * 4) = p0;
                    *(f32x4*)(gi_lds + (size_t)ti * GI_DW + d1 * 4) = p1;
                }
                const int t0p = t0n + 16;
                if (t0p < NT) {
                    #pragma unroll
                    for (int q = 0; q < 8; ++q)
                        xf[q] = x[xbase + (size_t)(g*8 + q) * NT + t0p + c];
                }
            }
        }

        // ---- windowed decode: 16 past h's, rotating duty wave ----
        if ((t & 15) == 0 && t >= 16 && wv == (((t >> 4) - 1) & 3)) {
            const short8* hq = (const short8*)(h_ring + (size_t)(((t - 16) & 31) + c) * HR_STRIDE);
            short8 AD0 = hq[0*4 + g];
            short8 AD1 = hq[1*4 + g];
            short8 AD2 = hq[2*4 + g];
            short8 AD3 = hq[3*4 + g];
            f32x4 aD1 = __builtin_amdgcn_mfma_f32_16x16x32_bf16(AD0, BD[0], zv, 0, 0, 0);
            f32x4 aD2 = __builtin_amdgcn_mfma_f32_16x16x32_bf16(AD2, BD[2], zv, 0, 0, 0);
            aD1 = __builtin_amdgcn_mfma_f32_16x16x32_bf16(AD1, BD[1], aD1, 0, 0, 0);
            aD2 = __builtin_amdgcn_mfma_f32_16x16x32_bf16(AD3, BD[3], aD2, 0, 0, 0);
            if (c == 0) {
                #pragma unroll
                for (int r = 0; r < 4; ++r)
                    out_lds[(t - 16) + 4*g + r] = aD1[r] + aD2[r];
            }
        }

        BAR_LGKM();
    }

    // ---- epilogue: decode h_{NT-16..NT-1} (ring slots 16..31) ----
    if (wv == 0) {
        const short8* hq = (const short8*)(h_ring + (size_t)(16 + c) * HR_STRIDE);
        short8 AD0 = hq[0*4 + g];
        short8 AD1 = hq[1*4 + g];
        short8 AD2 = hq[2*4 + g];
        short8 AD3 = hq[3*4 + g];
        f32x4 aD1 = __builtin_amdgcn_mfma_f32_16x16x32_bf16(AD0, BD[0], zv, 0, 0, 0);
        f32x4 aD2 = __builtin_amdgcn_mfma_f32_16x16x32_bf16(AD2, BD[2], zv, 0, 0, 0);
        aD1 = __builtin_amdgcn_mfma_f32_16x16x32_bf16(AD1, BD[1], aD1, 0, 0, 0);
        aD2 = __builtin_amdgcn_mfma_f32_16x16x32_bf16(AD3, BD[3], aD2, 0, 0, 0);
        if (c == 0) {
            #pragma unroll
            for (int r = 0; r < 4; ++r)
                out_lds[(NT - 16) + 4*g + r] = aD1[r] + aD2[r];
        }
    }
    __syncthreads();
    // ---- flush: fuse +xv and relu ----
    for (int i = tid; i < NT / 4; i += 256) {
        float4 o = ((const float4*)out_lds)[i];
        float4 v = ((const float4*)xv_lds)[i];
        float4 r;
        r.x = fmaxf(o.x + v.x, 0.0f);
        r.y = fmaxf(o.y + v.y, 0.0f);
        r.z = fmaxf(o.z + v.z, 0.0f);
        r.w = fmaxf(o.w + v.w, 0.0f);
        ((float4*)outb)[i] = r;
    }
}

extern "C" void kernel_launch(void* const* d_in, const int* in_sizes, int n_in,
                              void* d_out, int out_size, void* d_ws, size_t ws_size,
                              hipStream_t stream) {
    const float* x      = (const float*)d_in[0];
    const float* enc_w  = (const float*)d_in[1];
    const float* enc_b  = (const float*)d_in[2];
    const float* w_ih   = (const float*)d_in[3];
    const float* w_hh   = (const float*)d_in[4];
    const float* b_ih   = (const float*)d_in[5];
    const float* b_hh   = (const float*)d_in[6];
    const float* dec_w  = (const float*)d_in[7];
    const float* dec_b  = (const float*)d_in[8];
    const float* scale  = (const float*)d_in[9];
    const float* noise  = (const float*)d_in[10];
    float* out = (float*)d_out;

    k_xv<<<(NB * NT) / 256, 256, 0, stream>>>(x, enc_w, enc_b, dec_w, dec_b, scale, noise, out);
    k_gru<<<NB, 256, 0, stream>>>(x, enc_w, enc_b, w_ih, w_hh, b_ih, b_hh, dec_w, out);
}

// Round 3
// 1744.721 us; speedup vs baseline: 1.1887x; 1.0110x over previous
//
#include <hip/hip_runtime.h>

#define NB 64
#define NW 32
#define NT 4096
#define ND 128

#define GI_DW 516       // gi row stride in dwords: 128 dims * 4 (R,Z,N,pad) + 4 pad
#define HR_STRIDE 144   // h-ring row stride in shorts (288 B, 16B-aligned)

typedef __attribute__((ext_vector_type(8))) short short8;
typedef __attribute__((ext_vector_type(4))) float f32x4;

// workgroup barrier that drains LDS ops only (no vmcnt(0) drain):
// in-flight global prefetch loads stay outstanding across steps.
#define BAR_LGKM() asm volatile("s_waitcnt lgkmcnt(0)\n\ts_barrier" ::: "memory")

static __device__ __forceinline__ float sigm_f(float v) {
    float e = __builtin_amdgcn_exp2f(v * -1.4426950408889634f);
    return __builtin_amdgcn_rcpf(1.0f + e);
}
static __device__ __forceinline__ float tanh_f(float v) {
    float e = __builtin_amdgcn_exp2f(v * 2.8853900817779268f);
    return 1.0f - 2.0f * __builtin_amdgcn_rcpf(1.0f + e);
}
static __device__ __forceinline__ unsigned short f2bf(float f) {
    unsigned u = __float_as_uint(f);
    u += 0x7FFFu + ((u >> 16) & 1u);
    return (unsigned short)(u >> 16);
}
// single-instruction RNE f32->bf16 (low half of packed result); bit-identical to f2bf
static __device__ __forceinline__ unsigned cvt_pk_bf16(float a, float b) {
    unsigned r;
    asm("v_cvt_pk_bf16_f32 %0, %1, %2" : "=v"(r) : "v"(a), "v"(b));
    return r;
}

// Kernel 1: d_out[b*T+t] = c2 + scale*noise[b,t] + sum_w x[b,w,t]*v[w]
__global__ __launch_bounds__(256) void k_xv(
    const float* __restrict__ x, const float* __restrict__ enc_w,
    const float* __restrict__ enc_b, const float* __restrict__ dec_w,
    const float* __restrict__ dec_b, const float* __restrict__ scale,
    const float* __restrict__ noise, float* __restrict__ out)
{
    __shared__ float v_s[NW];
    __shared__ float c2_s;
    const int tid = threadIdx.x;
    if (tid < NW) {
        float s = 0.0f;
        for (int d = 0; d < ND; ++d) s = fmaf(enc_w[d * NW + tid], dec_w[d], s);
        v_s[tid] = s;
    } else if (tid == 64) {
        float s = 0.0f;
        for (int d = 0; d < ND; ++d) s = fmaf(enc_b[d], dec_w[d], s);
        c2_s = s + dec_b[0];
    }
    __syncthreads();
    const int flat = blockIdx.x * 256 + tid;   // flat = b*NT + t
    const int b = flat >> 12;
    const int t = flat & (NT - 1);
    float acc = c2_s + scale[0] * noise[flat];
    const float* xr = x + (size_t)b * NW * NT + t;
    #pragma unroll
    for (int w = 0; w < NW; ++w) acc = fmaf(xr[(size_t)w * NT], v_s[w], acc);
    out[flat] = acc;
}

// Kernel 2: one block per batch element, 512 threads = 8 waves.
// Waves 0-3 (consumers): pure recurrence. Per step: 4 HA b128 reads + next-step
// gi b128 prefetch + 24 MFMAs (R,N,Z order; gate VALU interleaved into the
// MFMA-issue shadow so the post-MFMA tail is only z_->h) + cvt_pk + h write.
// Waves 4-7 (producers): all windowed work off the critical waves — gi window
// GEMM at t%16==8, x prefetch, and decode split 1 MFMA/wave at staggered steps
// (t%16 == 4p+2) with barrier-ordered += into out_lds (no atomics, no skew).
__global__ __launch_bounds__(512, 1) void k_gru(
    const float* __restrict__ x, const float* __restrict__ enc_w,
    const float* __restrict__ enc_b, const float* __restrict__ w_ih,
    const float* __restrict__ w_hh, const float* __restrict__ b_ih,
    const float* __restrict__ b_hh, const float* __restrict__ dec_w,
    float* out)
{
    __shared__ alignas(16) float gi_lds[32 * GI_DW];               // 66048 B (aliases enc_w staging)
    __shared__ float encb_s[ND];
    __shared__ alignas(16) unsigned short h_ring[32 * HR_STRIDE];  // bf16, 32-slot ring, padded rows
    __shared__ alignas(16) float xv_lds[NT];                       // non-recurrent part
    __shared__ alignas(16) float out_lds[NT];                      // decode dots (accumulated)

    const int tid  = threadIdx.x;
    const int b    = blockIdx.x;
    const int wv   = tid >> 6;       // 0..7
    const int lane = tid & 63;
    const int g    = lane >> 4;      // k-group 0..3
    const int c    = lane & 15;      // column in 16-wide tile
    const int hi   = g & 1;          // which tile this lane's gate chain handles
    const int p    = wv - 4;         // producer index (valid for wv>=4)
    const int dg   = (wv < 4 ? wv : p);   // dim-group this wave owns
    const int d0   = dg * 32 + c;        // tile-0 owned hidden index
    const int d1   = d0 + 16;            // tile-1 owned hidden index
    const int dl   = dg * 32 + (lane & 31);  // consumer lane's gate dim

    const size_t xbase = (size_t)b * NW * NT;
    float* outb = out + (size_t)b * NT;
    float* encw_s = gi_lds;          // alias: init phase only

    // ---- init staging ----
    for (int i = tid; i < ND * NW; i += 512) encw_s[i] = enc_w[i];
    if (tid < ND) encb_s[tid] = enc_b[tid];
    for (int i = tid; i < 32 * HR_STRIDE; i += 512) h_ring[i] = 0;
    for (int i = tid; i < NT / 4; i += 512) {
        ((float4*)xv_lds)[i] = ((const float4*)outb)[i];
        ((float4*)out_lds)[i] = make_float4(0.f, 0.f, 0.f, 0.f);
    }
    __syncthreads();

    // ---- consumer state: w_hh B-frags + N-gate bias seeds ----
    short8 BR0[4], BZ0[4], BN0[4], BR1[4], BZ1[4], BN1[4];
    f32x4 cGNv0 = {0.f, 0.f, 0.f, 0.f}, cGNv1 = {0.f, 0.f, 0.f, 0.f};
    // ---- producer state: fused input B-frags, folded biases, decode frag, x pf ----
    short8 XR0, XZ0, XN0, XR1, XZ1, XN1, BDd;
    f32x4 cRv0, cZv0, cINv0, cRv1, cZv1, cINv1;
    float xf[8];
    const f32x4 zv = {0.f, 0.f, 0.f, 0.f};

    if (wv < 4) {
        #pragma unroll
        for (int kt = 0; kt < 4; ++kt) {
            const float* pr0 = w_hh + (size_t)(0*ND + d0) * ND + kt*32 + g*8;
            const float* pz0 = w_hh + (size_t)(1*ND + d0) * ND + kt*32 + g*8;
            const float* pn0 = w_hh + (size_t)(2*ND + d0) * ND + kt*32 + g*8;
            const float* pr1 = w_hh + (size_t)(0*ND + d1) * ND + kt*32 + g*8;
            const float* pz1 = w_hh + (size_t)(1*ND + d1) * ND + kt*32 + g*8;
            const float* pn1 = w_hh + (size_t)(2*ND + d1) * ND + kt*32 + g*8;
            #pragma unroll
            for (int i = 0; i < 8; ++i) {
                BR0[kt][i] = (short)f2bf(pr0[i]);
                BZ0[kt][i] = (short)f2bf(pz0[i]);
                BN0[kt][i] = (short)f2bf(pn0[i]);
                BR1[kt][i] = (short)f2bf(pr1[i]);
                BZ1[kt][i] = (short)f2bf(pz1[i]);
                BN1[kt][i] = (short)f2bf(pn1[i]);
            }
        }
        float g0 = b_hh[2*ND + d0], g1 = b_hh[2*ND + d1];
        cGNv0 = (f32x4){g0, g0, g0, g0};
        cGNv1 = (f32x4){g1, g1, g1, g1};
    } else {
        // fused input B-frags: M[w][j] = sum_dp enc_w[dp][w]*w_ih[j][dp]
        const float* rr0 = w_ih + (size_t)(0*ND + d0) * ND;
        const float* rz0 = w_ih + (size_t)(1*ND + d0) * ND;
        const float* rn0 = w_ih + (size_t)(2*ND + d0) * ND;
        const float* rr1 = w_ih + (size_t)(0*ND + d1) * ND;
        const float* rz1 = w_ih + (size_t)(1*ND + d1) * ND;
        const float* rn1 = w_ih + (size_t)(2*ND + d1) * ND;
        #pragma unroll
        for (int i = 0; i < 8; ++i) {
            int w = g*8 + i;
            float ar0 = 0.f, az0 = 0.f, an0 = 0.f, ar1 = 0.f, az1 = 0.f, an1 = 0.f;
            for (int dp = 0; dp < ND; ++dp) {
                float ew = encw_s[dp*NW + w];
                ar0 = fmaf(ew, rr0[dp], ar0);
                az0 = fmaf(ew, rz0[dp], az0);
                an0 = fmaf(ew, rn0[dp], an0);
                ar1 = fmaf(ew, rr1[dp], ar1);
                az1 = fmaf(ew, rz1[dp], az1);
                an1 = fmaf(ew, rn1[dp], an1);
            }
            XR0[i] = (short)f2bf(ar0); XZ0[i] = (short)f2bf(az0); XN0[i] = (short)f2bf(an0);
            XR1[i] = (short)f2bf(ar1); XZ1[i] = (short)f2bf(az1); XN1[i] = (short)f2bf(an1);
        }
        // folded biases
        float a0 = b_ih[d0], a1 = b_ih[ND+d0], a2 = b_ih[2*ND+d0];
        float e0 = b_ih[d1], e1 = b_ih[ND+d1], e2 = b_ih[2*ND+d1];
        for (int dp = 0; dp < ND; ++dp) {
            float eb = encb_s[dp];
            a0 = fmaf(eb, rr0[dp], a0);
            a1 = fmaf(eb, rz0[dp], a1);
            a2 = fmaf(eb, rn0[dp], a2);
            e0 = fmaf(eb, rr1[dp], e0);
            e1 = fmaf(eb, rz1[dp], e1);
            e2 = fmaf(eb, rn1[dp], e2);
        }
        float cR0 = a0 + b_hh[d0],  cZ0 = a1 + b_hh[ND+d0];
        float cR1 = e0 + b_hh[d1],  cZ1 = e1 + b_hh[ND+d1];
        cRv0 = (f32x4){cR0, cR0, cR0, cR0};
        cZv0 = (f32x4){cZ0, cZ0, cZ0, cZ0};
        cINv0 = (f32x4){a2, a2, a2, a2};
        cRv1 = (f32x4){cR1, cR1, cR1, cR1};
        cZv1 = (f32x4){cZ1, cZ1, cZ1, cZ1};
        cINv1 = (f32x4){e2, e2, e2, e2};
        // decode B-frag: this wave's K-slice kt=p
        #pragma unroll
        for (int i = 0; i < 8; ++i) BDd[i] = (short)f2bf(dec_w[p*32 + g*8 + i]);
    }

    __syncthreads();   // producers done reading encw_s before gi_lds overwrite

    // ---- prologue (producers): window 0 gi GEMM, preload window-1 x ----
    if (wv >= 4) {
        #pragma unroll
        for (int q = 0; q < 8; ++q)
            xf[q] = x[xbase + (size_t)(g*8 + q) * NT + c];
        short8 xA;
        #pragma unroll
        for (int i = 0; i < 8; ++i) xA[i] = (short)f2bf(xf[i]);
        f32x4 gR0 = __builtin_amdgcn_mfma_f32_16x16x32_bf16(xA, XR0, cRv0, 0, 0, 0);
        f32x4 gZ0 = __builtin_amdgcn_mfma_f32_16x16x32_bf16(xA, XZ0, cZv0, 0, 0, 0);
        f32x4 gN0 = __builtin_amdgcn_mfma_f32_16x16x32_bf16(xA, XN0, cINv0, 0, 0, 0);
        f32x4 gR1 = __builtin_amdgcn_mfma_f32_16x16x32_bf16(xA, XR1, cRv1, 0, 0, 0);
        f32x4 gZ1 = __builtin_amdgcn_mfma_f32_16x16x32_bf16(xA, XZ1, cZv1, 0, 0, 0);
        f32x4 gN1 = __builtin_amdgcn_mfma_f32_16x16x32_bf16(xA, XN1, cINv1, 0, 0, 0);
        #pragma unroll
        for (int r = 0; r < 4; ++r) {
            int ti = 4*g + r;
            f32x4 p0 = {gR0[r], gZ0[r], gN0[r], 0.f};
            f32x4 p1 = {gR1[r], gZ1[r], gN1[r], 0.f};
            *(f32x4*)(gi_lds + (size_t)ti * GI_DW + d0 * 4) = p0;
            *(f32x4*)(gi_lds + (size_t)ti * GI_DW + d1 * 4) = p1;
        }
        #pragma unroll
        for (int q = 0; q < 8; ++q)
            xf[q] = x[xbase + (size_t)(g*8 + q) * NT + 16 + c];
    }

    __syncthreads();

    float h = 0.0f;
    f32x4 giv = *(const f32x4*)(gi_lds + dl * 4);   // gi for t=0

    #pragma unroll 1
    for (int t = 0; t < NT; ++t) {
        if (wv < 4) {
            // ---- h A-frags (broadcast b128 reads, ring slot (t-1)&31) ----
            const short8* hp = (const short8*)(h_ring + (size_t)((t + 31) & 31) * HR_STRIDE);
            const short8 HA0 = hp[0*4 + g];
            const short8 HA1 = hp[1*4 + g];
            const short8 HA2 = hp[2*4 + g];
            const short8 HA3 = hp[3*4 + g];
            // prefetch next step's gi (written >=7 steps ago; latency hidden here)
            const f32x4 gi_next = *(const f32x4*)(gi_lds + (size_t)((t + 1) & 31) * GI_DW + dl * 4);

            // ---- R MFMAs ----
            f32x4 aR1_0 = __builtin_amdgcn_mfma_f32_16x16x32_bf16(HA0, BR0[0], zv, 0, 0, 0);
            f32x4 aR2_0 = __builtin_amdgcn_mfma_f32_16x16x32_bf16(HA2, BR0[2], zv, 0, 0, 0);
            f32x4 aR1_1 = __builtin_amdgcn_mfma_f32_16x16x32_bf16(HA0, BR1[0], zv, 0, 0, 0);
            f32x4 aR2_1 = __builtin_amdgcn_mfma_f32_16x16x32_bf16(HA2, BR1[2], zv, 0, 0, 0);
            aR1_0 = __builtin_amdgcn_mfma_f32_16x16x32_bf16(HA1, BR0[1], aR1_0, 0, 0, 0);
            aR2_0 = __builtin_amdgcn_mfma_f32_16x16x32_bf16(HA3, BR0[3], aR2_0, 0, 0, 0);
            aR1_1 = __builtin_amdgcn_mfma_f32_16x16x32_bf16(HA1, BR1[1], aR1_1, 0, 0, 0);
            aR2_1 = __builtin_amdgcn_mfma_f32_16x16x32_bf16(HA3, BR1[3], aR2_1, 0, 0, 0);
            // ---- N MFMAs (GN needed with r_ for tanh) ----
            f32x4 aN1_0 = __builtin_amdgcn_mfma_f32_16x16x32_bf16(HA0, BN0[0], cGNv0, 0, 0, 0);
            f32x4 aN2_0 = __builtin_amdgcn_mfma_f32_16x16x32_bf16(HA2, BN0[2], zv, 0, 0, 0);
            f32x4 aN1_1 = __builtin_amdgcn_mfma_f32_16x16x32_bf16(HA0, BN1[0], cGNv1, 0, 0, 0);
            f32x4 aN2_1 = __builtin_amdgcn_mfma_f32_16x16x32_bf16(HA2, BN1[2], zv, 0, 0, 0);
            aN1_0 = __builtin_amdgcn_mfma_f32_16x16x32_bf16(HA1, BN0[1], aN1_0, 0, 0, 0);
            aN2_0 = __builtin_amdgcn_mfma_f32_16x16x32_bf16(HA3, BN0[3], aN2_0, 0, 0, 0);
            aN1_1 = __builtin_amdgcn_mfma_f32_16x16x32_bf16(HA1, BN1[1], aN1_1, 0, 0, 0);
            aN2_1 = __builtin_amdgcn_mfma_f32_16x16x32_bf16(HA3, BN1[3], aN2_1, 0, 0, 0);

            // ---- r_ in the Z-MFMA issue shadow ----
            float Rs = (hi ? aR1_1[0] : aR1_0[0]) + (hi ? aR2_1[0] : aR2_0[0]);
            float r_ = sigm_f(Rs + giv[0]);

            // ---- Z MFMAs ----
            f32x4 aZ1_0 = __builtin_amdgcn_mfma_f32_16x16x32_bf16(HA0, BZ0[0], zv, 0, 0, 0);
            f32x4 aZ2_0 = __builtin_amdgcn_mfma_f32_16x16x32_bf16(HA2, BZ0[2], zv, 0, 0, 0);
            f32x4 aZ1_1 = __builtin_amdgcn_mfma_f32_16x16x32_bf16(HA0, BZ1[0], zv, 0, 0, 0);
            f32x4 aZ2_1 = __builtin_amdgcn_mfma_f32_16x16x32_bf16(HA2, BZ1[2], zv, 0, 0, 0);
            aZ1_0 = __builtin_amdgcn_mfma_f32_16x16x32_bf16(HA1, BZ0[1], aZ1_0, 0, 0, 0);
            aZ2_0 = __builtin_amdgcn_mfma_f32_16x16x32_bf16(HA3, BZ0[3], aZ2_0, 0, 0, 0);
            aZ1_1 = __builtin_amdgcn_mfma_f32_16x16x32_bf16(HA1, BZ1[1], aZ1_1, 0, 0, 0);
            aZ2_1 = __builtin_amdgcn_mfma_f32_16x16x32_bf16(HA3, BZ1[3], aZ2_1, 0, 0, 0);

            // ---- tail: n_ then z_ then h ----
            float GNs = (hi ? aN1_1[0] : aN1_0[0]) + (hi ? aN2_1[0] : aN2_0[0]);
            float n_ = tanh_f(fmaf(r_, GNs, giv[2]));
            float Zs = (hi ? aZ1_1[0] : aZ1_0[0]) + (hi ? aZ2_1[0] : aZ2_0[0]);
            float z_ = sigm_f(Zs + giv[1]);
            h = fmaf(z_, h - n_, n_);            // (1-z)*n + z*h
            unsigned hpk = cvt_pk_bf16(h, h);
            if (lane < 32) h_ring[(size_t)(t & 31) * HR_STRIDE + dl] = (unsigned short)hpk;
            giv = gi_next;
        } else {
            // ---- producer duties, off the critical waves ----
            if ((t & 15) == 8) {
                const int t0n = (t & ~15) + 16;
                if (t0n < NT) {
                    short8 xA;
                    #pragma unroll
                    for (int i = 0; i < 8; ++i) xA[i] = (short)f2bf(xf[i]);
                    f32x4 gR0 = __builtin_amdgcn_mfma_f32_16x16x32_bf16(xA, XR0, cRv0, 0, 0, 0);
                    f32x4 gZ0 = __builtin_amdgcn_mfma_f32_16x16x32_bf16(xA, XZ0, cZv0, 0, 0, 0);
                    f32x4 gN0 = __builtin_amdgcn_mfma_f32_16x16x32_bf16(xA, XN0, cINv0, 0, 0, 0);
                    f32x4 gR1 = __builtin_amdgcn_mfma_f32_16x16x32_bf16(xA, XR1, cRv1, 0, 0, 0);
                    f32x4 gZ1 = __builtin_amdgcn_mfma_f32_16x16x32_bf16(xA, XZ1, cZv1, 0, 0, 0);
                    f32x4 gN1 = __builtin_amdgcn_mfma_f32_16x16x32_bf16(xA, XN1, cINv1, 0, 0, 0);
                    const int rb = t0n & 31;
                    #pragma unroll
                    for (int r = 0; r < 4; ++r) {
                        int ti = rb + 4*g + r;
                        f32x4 p0 = {gR0[r], gZ0[r], gN0[r], 0.f};
                        f32x4 p1 = {gR1[r], gZ1[r], gN1[r], 0.f};
                        *(f32x4*)(gi_lds + (size_t)ti * GI_DW + d0 * 4) = p0;
                        *(f32x4*)(gi_lds + (size_t)ti * GI_DW + d1 * 4) = p1;
                    }
                    const int t0p = t0n + 16;
                    if (t0p < NT) {
                        #pragma unroll
                        for (int q = 0; q < 8; ++q)
                            xf[q] = x[xbase + (size_t)(g*8 + q) * NT + t0p + c];
                    }
                }
            }
            // staggered decode: wave p handles K-slice kt=p of window [t0w, t0w+16)
            // at t%16 == 4p+2 — barrier-ordered exclusive += (no atomics)
            if ((t & 15) == (p * 4 + 2) && t >= 16) {
                const int t0w = (t & ~15) - 16;
                const short8* hq = (const short8*)(h_ring + (size_t)((t0w & 31) + c) * HR_STRIDE);
                short8 AD = hq[p*4 + g];
                f32x4 aD = __builtin_amdgcn_mfma_f32_16x16x32_bf16(AD, BDd, zv, 0, 0, 0);
                if (c == 0) {
                    #pragma unroll
                    for (int r = 0; r < 4; ++r)
                        out_lds[t0w + 4*g + r] += aD[r];
                }
            }
        }
        BAR_LGKM();
    }

    // ---- epilogue: decode last window (ring slots 16..31), single producer wave ----
    if (wv == 4) {
        short8 BDk[4];
        #pragma unroll
        for (int kt = 0; kt < 4; ++kt)
            #pragma unroll
            for (int i = 0; i < 8; ++i)
                BDk[kt][i] = (short)f2bf(dec_w[kt*32 + g*8 + i]);
        const short8* hq = (const short8*)(h_ring + (size_t)(16 + c) * HR_STRIDE);
        short8 AD0 = hq[0*4 + g];
        short8 AD1 = hq[1*4 + g];
        short8 AD2 = hq[2*4 + g];
        short8 AD3 = hq[3*4 + g];
        f32x4 aD1 = __builtin_amdgcn_mfma_f32_16x16x32_bf16(AD0, BDk[0], zv, 0, 0, 0);
        f32x4 aD2 = __builtin_amdgcn_mfma_f32_16x16x32_bf16(AD2, BDk[2], zv, 0, 0, 0);
        aD1 = __builtin_amdgcn_mfma_f32_16x16x32_bf16(AD1, BDk[1], aD1, 0, 0, 0);
        aD2 = __builtin_amdgcn_mfma_f32_16x16x32_bf16(AD3, BDk[3], aD2, 0, 0, 0);
        if (c == 0) {
            #pragma unroll
            for (int r = 0; r < 4; ++r)
                out_lds[(NT - 16) + 4*g + r] = aD1[r] + aD2[r];
        }
    }
    __syncthreads();
    // ---- flush: fuse +xv and relu ----
    for (int i = tid; i < NT / 4; i += 512) {
        float4 o = ((const float4*)out_lds)[i];
        float4 v = ((const float4*)xv_lds)[i];
        float4 r;
        r.x = fmaxf(o.x + v.x, 0.0f);
        r.y = fmaxf(o.y + v.y, 0.0f);
        r.z = fmaxf(o.z + v.z, 0.0f);
        r.w = fmaxf(o.w + v.w, 0.0f);
        ((float4*)outb)[i] = r;
    }
}

extern "C" void kernel_launch(void* const* d_in, const int* in_sizes, int n_in,
                              void* d_out, int out_size, void* d_ws, size_t ws_size,
                              hipStream_t stream) {
    const float* x      = (const float*)d_in[0];
    const float* enc_w  = (const float*)d_in[1];
    const float* enc_b  = (const float*)d_in[2];
    const float* w_ih   = (const float*)d_in[3];
    const float* w_hh   = (const float*)d_in[4];
    const float* b_ih   = (const float*)d_in[5];
    const float* b_hh   = (const float*)d_in[6];
    const float* dec_w  = (const float*)d_in[7];
    const float* dec_b  = (const float*)d_in[8];
    const float* scale  = (const float*)d_in[9];
    const float* noise  = (const float*)d_in[10];
    float* out = (float*)d_out;

    k_xv<<<(NB * NT) / 256, 256, 0, stream>>>(x, enc_w, enc_b, dec_w, dec_b, scale, noise, out);
    k_gru<<<NB, 512, 0, stream>>>(x, enc_w, enc_b, w_ih, w_hh, b_ih, b_hh, dec_w, out);
}